// Round 12
// baseline (214.777 us; speedup 1.0000x reference)
//
#include <hip/hip_runtime.h>
#include <hip/hip_bf16.h>

// SelfAttention B=2,N=4096,E=512,H=8,D=64 — Round 22:
// R19-R21: attn pinned at ~43/43 MfmaUtil/VALUBusy under every schedule
// (occupancy, prefetch depth, fences all neutral) -> attack the MFMA shape.
// R22: attn on 32x32x16 MFMA (ceiling 2495 vs 2075 TF; 2x FLOP/instr):
//  - wave = qh(64q) x kh(32kcol); S^T = mfma32(K, Q): lane's q = lane&31
//    matches PV A-frag m exactly -> P lane-local.
//  - PV A-kslot j <- D-reg j requires kcol bit2<->bit3 swap: folded into K
//    staging row address (zero cost, self-inverse). V natural order.
//  - 20 MFMA/wave/kt (8 QK + 8 PV + 4 ones) vs 36; exp2/pack unchanged;
//    l read straight from ones-D in epilogue.
//  - sync skeleton = R21 (3 buffers, vmcnt(4), no fences). Others unchanged.

#define ROWS 8192
#define EMB  512
#define SEQ  4096
#define HEADS 8
#define HD   64
#define QSCALE 0.18033688011112042f   // 0.125 * log2(e)

typedef __attribute__((ext_vector_type(8))) short bf16x8;
typedef __attribute__((ext_vector_type(4))) short bf16x4;
typedef __attribute__((ext_vector_type(4))) float f32x4;
typedef __attribute__((ext_vector_type(16))) float f32x16;

#define MFMA32(A, B, C) __builtin_amdgcn_mfma_f32_32x32x16_bf16(A, B, C, 0, 0, 0)

__device__ __forceinline__ float bf16_to_f(unsigned short u) {
    union { unsigned int i; float f; } v; v.i = ((unsigned int)u) << 16; return v.f;
}
__device__ __forceinline__ unsigned short f_to_bf16(float f) {
    union { __hip_bfloat16 h; unsigned short u; } v; v.h = __float2bfloat16(f); return v.u;
}
// low16 = hi16(a), high16 = hi16(b) — single v_perm_b32
__device__ __forceinline__ unsigned int pack_bf16_trunc(float a, float b) {
    return __builtin_amdgcn_perm(__float_as_uint(b), __float_as_uint(a), 0x07060302u);
}
__device__ __forceinline__ void load_lds16(const void* g, void* l) {
    __builtin_amdgcn_global_load_lds(
        (const __attribute__((address_space(1))) void*)g,
        (__attribute__((address_space(3))) void*)l, 16, 0, 0);
}

// ---- inline dtype detection: fp32 buffers have wild "exponents" in halfwords.
__device__ __forceinline__ int detect_fp32(const void* x) {
    const unsigned short* p = (const unsigned short*)x;
    int t = threadIdx.x & 63;
    int cnt = 0;
    #pragma unroll
    for (int i = 0; i < 4; ++i) {
        unsigned short u = p[t * 4 + i];
        int e = (u >> 7) & 0xFF;
        cnt += (e >= 140) ? 1 : 0;
    }
    #pragma unroll
    for (int off = 32; off > 0; off >>= 1) cnt += __shfl_xor(cnt, off, 64);
    return cnt > 16;
}

// ---- fused prep: [0,4096) conv_x | [4096,4352) conv_wt | [4352,4364) conv_small
__global__ __launch_bounds__(256) void prep_kernel(
        const void* __restrict__ x, unsigned short* __restrict__ xb,
        const void* W0, const void* W1, const void* W2, const void* W3,
        unsigned short* __restrict__ Wt,
        const void* b0, const void* b1, const void* b2, const void* b3,
        const void* b4, const void* b5, float* __restrict__ bias_all) {
    int fp32 = detect_fp32(x);
    int bid = blockIdx.x;
    int tid = threadIdx.x;
    if (bid < 4096) {                       // ---- conv_x: x -> xb (bf16)
        if (!fp32) return;
        int i = (bid * 256 + tid) * 4;
        float4 v = *(const float4*)((const float*)x + i);
        ushort4 u = { f_to_bf16(v.x), f_to_bf16(v.y), f_to_bf16(v.z), f_to_bf16(v.w) };
        *(ushort4*)(xb + i) = u;
    } else if (bid < 4352) {                // ---- conv_wt: W[K][N] -> Wt[n][k]
        __shared__ float T[64][65];
        int idx0 = bid - 4096;
        int kt = idx0 & 7, nt = (idx0 >> 3) & 7, mat = idx0 >> 6;
        const void* src = (mat == 0) ? W0 : (mat == 1) ? W1 : (mat == 2) ? W2 : W3;
        for (int ii = 0; ii < 4; ++ii) {
            int idx = tid + ii * 256;
            int i = idx >> 4, j = (idx & 15) * 4;
            size_t g = (size_t)(kt * 64 + i) * 512 + nt * 64 + j;
            if (fp32) {
                float4 v = *(const float4*)((const float*)src + g);
                T[i][j] = v.x; T[i][j+1] = v.y; T[i][j+2] = v.z; T[i][j+3] = v.w;
            } else {
                ushort4 u = *(const ushort4*)((const unsigned short*)src + g);
                T[i][j] = bf16_to_f(u.x); T[i][j+1] = bf16_to_f(u.y);
                T[i][j+2] = bf16_to_f(u.z); T[i][j+3] = bf16_to_f(u.w);
            }
        }
        __syncthreads();
        for (int ii = 0; ii < 2; ++ii) {
            int idx = tid + ii * 256;
            int j = idx >> 3, ch = idx & 7;
            unsigned short pk[8];
            for (int t = 0; t < 8; ++t) pk[t] = f_to_bf16(T[ch * 8 + t][j]);
            *(bf16x8*)&Wt[(size_t)(mat * 512 + nt * 64 + j) * 512 + kt * 64 + ch * 8] = *(bf16x8*)pk;
        }
    } else {                                // ---- conv_small: 6 vecs -> bias_all
        int idx = (bid - 4352) * 256 + tid;
        int mat = idx >> 9, off = idx & 511;
        const void* src = (mat == 0) ? b0 : (mat == 1) ? b1 : (mat == 2) ? b2 :
                          (mat == 3) ? b3 : (mat == 4) ? b4 : b5;
        float v;
        if (fp32) v = ((const float*)src)[off];
        else      v = bf16_to_f(((const unsigned short*)src)[off]);
        bias_all[idx] = v;
    }
}

// ---- MFMA GEMM (QKV only): C = A * Bt^T + bias, 128x128x64 tiles,
// 2-phase double-buffered. Epilogue: LDS re-tile -> coalesced stores.
// C-blocks use swapped mfma(b,a); V-blocks (VtOut && n0>=1024) classic order.
template <typename OutT>
__global__ __launch_bounds__(256) void gemm_mfma_kernel(
        const unsigned short* __restrict__ A_conv, const unsigned short* __restrict__ A_raw,
        const unsigned short* __restrict__ Bt,
        const float* __restrict__ bias, OutT* __restrict__ C, int ldc, int scale_cols,
        unsigned short* __restrict__ VtOut) {
    __shared__ __align__(16) unsigned short smemg[2][2][128 * 64];  // [buf][A/B] 64KB
    const unsigned short* A = detect_fp32(A_raw) ? A_conv : A_raw;
    int tid = threadIdx.x;
    int wave = tid >> 6, lane = tid & 63;
    int l15 = lane & 15, quad = lane >> 4;

    int lin = blockIdx.x + gridDim.x * blockIdx.y;
    int nwg = gridDim.x * gridDim.y;
    int bx, by;
    if (nwg & 7) { bx = blockIdx.x; by = blockIdx.y; }
    else {
        int t = (lin & 7) * (nwg >> 3) + (lin >> 3);
        bx = t % gridDim.x; by = t / gridDim.x;
    }
    int m0 = by * 128, n0 = bx * 128;
    int wm = (wave & 1) * 64, wn = (wave >> 1) * 64;
    bool is_v = (VtOut != nullptr) && (n0 >= 1024);

    int rt = wave * 32 + (lane >> 3);
    int ch = (lane & 7) ^ ((lane >> 3) & 7);
    const unsigned short* ag = A  + (size_t)(m0 + rt) * 512 + ch * 8;
    const unsigned short* bg = Bt + (size_t)(n0 + rt) * 512 + ch * 8;

    f32x4 acc[4][4];
    for (int i = 0; i < 4; ++i) for (int j = 0; j < 4; ++j) acc[i][j] = (f32x4){0.f,0.f,0.f,0.f};

#define GSTAGE(buf, k0) do {                                                      \
        unsigned short* Atb = &smemg[buf][0][0];                                  \
        unsigned short* Bsb = &smemg[buf][1][0];                                  \
        _Pragma("unroll")                                                         \
        for (int j = 0; j < 4; ++j) {                                             \
            load_lds16(ag + (size_t)(j * 8) * 512 + (k0), &Atb[(wave * 32 + j * 8) * 64]); \
            load_lds16(bg + (size_t)(j * 8) * 512 + (k0), &Bsb[(wave * 32 + j * 8) * 64]); \
        }                                                                         \
    } while (0)

    GSTAGE(0, 0);   // prologue

    for (int s = 0; s < 8; ++s) {
        int cur = s & 1;
        asm volatile("s_waitcnt vmcnt(0)" ::: "memory");
        __builtin_amdgcn_sched_barrier(0);
        asm volatile("s_barrier" ::: "memory");
        __builtin_amdgcn_sched_barrier(0);
        if (s + 1 < 8) GSTAGE(cur ^ 1, (s + 1) * 64);   // in flight during compute

        const unsigned short* At = &smemg[cur][0][0];
        const unsigned short* Bs = &smemg[cur][1][0];
        #pragma unroll
        for (int ks = 0; ks < 2; ++ks) {
            bf16x8 a[4], b[4];
            #pragma unroll
            for (int f = 0; f < 4; ++f) {
                int pc = ((ks * 4 + quad) ^ (l15 & 7)) * 8;
                a[f] = *(const bf16x8*)&At[(wm + f * 16 + l15) * 64 + pc];
                b[f] = *(const bf16x8*)&Bs[(wn + f * 16 + l15) * 64 + pc];
            }
            if (is_v) {
                #pragma unroll
                for (int fm = 0; fm < 4; ++fm)
                    #pragma unroll
                    for (int fn = 0; fn < 4; ++fn)
                        acc[fm][fn] = __builtin_amdgcn_mfma_f32_16x16x32_bf16(a[fm], b[fn], acc[fm][fn], 0, 0, 0);
            } else {
                #pragma unroll
                for (int fm = 0; fm < 4; ++fm)
                    #pragma unroll
                    for (int fn = 0; fn < 4; ++fn)
                        acc[fm][fn] = __builtin_amdgcn_mfma_f32_16x16x32_bf16(b[fn], a[fm], acc[fm][fn], 0, 0, 0);
            }
        }
        __builtin_amdgcn_sched_barrier(0);
    }
#undef GSTAGE

    // ---- epilogue: LDS re-tile (32KB, aliases dbuf) -> coalesced stores
    __syncthreads();
    unsigned short* LT = &smemg[0][0][0];   // [128 rows][128 ushorts], 8B-chunk swizzle

    float sc = (n0 < scale_cols) ? QSCALE : 1.f;

    if (is_v) {
        #pragma unroll
        for (int fm = 0; fm < 4; ++fm) {
            #pragma unroll
            for (int fn = 0; fn < 4; ++fn) {
                int dcol = wn + fn * 16 + l15;
                float bia = bias[n0 + dcol];
                int seq0 = wm + fm * 16 + quad * 4;
                ushort4 pk = { f_to_bf16(acc[fm][fn][0] + bia),
                               f_to_bf16(acc[fm][fn][1] + bia),
                               f_to_bf16(acc[fm][fn][2] + bia),
                               f_to_bf16(acc[fm][fn][3] + bia) };
                int c8 = (seq0 >> 2) ^ (dcol & 31);
                *(ushort4*)&LT[dcol * 128 + c8 * 4] = pk;
            }
        }
    } else {
        #pragma unroll
        for (int fm = 0; fm < 4; ++fm) {
            #pragma unroll
            for (int fn = 0; fn < 4; ++fn) {
                int row = wm + fm * 16 + l15;
                int col0 = wn + fn * 16 + quad * 4;
                float4 b4 = *(const float4*)&bias[n0 + col0];
                ushort4 pk = { f_to_bf16((acc[fm][fn][0] + b4.x) * sc),
                               f_to_bf16((acc[fm][fn][1] + b4.y) * sc),
                               f_to_bf16((acc[fm][fn][2] + b4.z) * sc),
                               f_to_bf16((acc[fm][fn][3] + b4.w) * sc) };
                int c8 = (col0 >> 2) ^ (row & 31);
                *(ushort4*)&LT[row * 128 + c8 * 4] = pk;
            }
        }
    }
    __syncthreads();
    #pragma unroll
    for (int i = 0; i < 16; ++i) {
        int row = wave * 32 + i * 2 + (lane >> 5);
        int c8 = lane & 31;
        int phys = c8 ^ (row & 31);
        ushort4 v4 = *(const ushort4*)&LT[row * 128 + phys * 4];
        if (is_v) {
            int hd = n0 - 1024 + row;
            int bh = (m0 >> 12) * 8 + (hd >> 6);
            int d  = hd & 63;
            *(ushort4*)&VtOut[((size_t)(bh * 64 + d)) * SEQ + (m0 & 4095) + c8 * 4] = v4;
        } else {
            *(ushort4*)&C[(size_t)(m0 + row) * ldc + n0 + c8 * 4] = v4;
        }
    }
}

// ---- MFMA flash attention, 32x32x16 MFMA, 3 LDS buffers, 128 q per block.
// Wave = qh(64q = 2 tiles) x kh(32 kcols). S^T = mfma32(K, Q): D col = q =
// lane&31 (= PV A-frag m). K rows staged with bit2<->3 swap so D-reg j feeds
// PV A-kslot j directly; V natural order. l via ones-MFMA (D row = q).
__global__ __launch_bounds__(256, 2) void attn_kernel(
        const unsigned short* __restrict__ QKV, const unsigned short* __restrict__ Vt,
        unsigned short* __restrict__ Ab) {
    __shared__ __align__(16) unsigned char smem[49152];   // Ks[3]@0, Vs[3]@24576
    // epilogue aliases: Ored f32 [4 w][32 q][64 d] @0 (32KB), Lred @32768 (1KB)

    int tid = threadIdx.x;
    int wave = tid >> 6, lane = tid & 63;
    int l31 = lane & 31, lh = lane >> 5;
    int qh = wave >> 1, kh = wave & 1;
    int lin = blockIdx.x;                 // 512 = 8 xcd * 64 slots
    int xcd = lin & 7, slot = lin >> 3;
    int grp = xcd + 8 * (slot >> 5);      // 16 (b,h) groups, 2 per XCD
    int qt0 = slot & 31;
    int h = grp & 7, b = grp >> 3;
    int bh = b * HEADS + h;
    size_t qrow0 = (size_t)b * SEQ + qt0 * 128;

    // Q B-frags (n = q = l31, k = d): aq[qt][ks]: q = qh*64 + qt*32 + l31,
    // d = ks*16 + lh*8 .. +8. Pre-scaled by QSCALE.
    bf16x8 aq[2][4];
    #pragma unroll
    for (int qt = 0; qt < 2; ++qt) {
        const unsigned short* qp = &QKV[(qrow0 + qh * 64 + qt * 32 + l31) * 1536 + h * 64];
        #pragma unroll
        for (int ks = 0; ks < 4; ++ks)
            aq[qt][ks] = *(const bf16x8*)&qp[ks * 16 + lh * 8];
    }
    f32x16 o[2][2];    // [qt][dt]: O[q tile][d tile], partial over kh
    f32x16 ol[2];      // [qt]: l (rows = q, cols all equal)
    #pragma unroll
    for (int qt = 0; qt < 2; ++qt) {
        #pragma unroll
        for (int dt = 0; dt < 2; ++dt)
            #pragma unroll
            for (int i = 0; i < 16; ++i) o[qt][dt][i] = 0.f;
        #pragma unroll
        for (int i = 0; i < 16; ++i) ol[qt][i] = 0.f;
    }
    const bf16x8 ones8 = { (short)0x3F80, (short)0x3F80, (short)0x3F80, (short)0x3F80,
                           (short)0x3F80, (short)0x3F80, (short)0x3F80, (short)0x3F80 };

    // staging. K rows permuted: physical row p holds global kcol swap23(p).
    int r8 = lane >> 3;
    int kch = (lane & 7) ^ (r8 & 7);
    int p0 = wave * 16 + r8;
    int p1 = p0 + 8;
    int s0 = (p0 & ~12) | ((p0 & 4) << 1) | ((p0 & 8) >> 1);
    int s1 = (p1 & ~12) | ((p1 & 4) << 1) | ((p1 & 8) >> 1);
    const unsigned short* kg0 = &QKV[((size_t)b * SEQ + s0) * 1536 + 512 + h * 64 + kch * 8];
    const unsigned short* kg1 = &QKV[((size_t)b * SEQ + s1) * 1536 + 512 + h * 64 + kch * 8];
    const unsigned short* vg = &Vt[((size_t)bh * 64 + wave * 16 + r8) * SEQ + kch * 8];

#define STAGE(buf, kt2) do {                                                          \
        unsigned short* Ksb = (unsigned short*)(smem + (buf) * 8192);                 \
        unsigned short* Vsb = (unsigned short*)(smem + 24576 + (buf) * 8192);         \
        load_lds16(kg0 + (size_t)((kt2) * 64) * 1536, &Ksb[(wave * 16) * 64]);        \
        load_lds16(kg1 + (size_t)((kt2) * 64) * 1536, &Ksb[(wave * 16 + 8) * 64]);    \
        load_lds16(vg + (size_t)((kt2) * 64), &Vsb[(wave * 16) * 64]);                \
        load_lds16(vg + (size_t)((kt2) * 64) + (size_t)8 * SEQ,                       \
                   &Vsb[(wave * 16 + 8) * 64]);                                       \
    } while (0)

    STAGE(0, 0);   // prologue: depth-2
    STAGE(1, 1);

    int cur = 0;
    for (int kt = 0; kt < SEQ / 64; ++kt) {
        if (kt + 1 < SEQ / 64) {
            asm volatile("s_waitcnt vmcnt(4)" ::: "memory");
        } else {
            asm volatile("s_waitcnt vmcnt(0)" ::: "memory");
        }
        asm volatile("s_barrier" ::: "memory");
        if (kt + 2 < SEQ / 64) {
            int nb2 = cur + 2; if (nb2 >= 3) nb2 -= 3;
            STAGE(nb2, kt + 2);
        }

        const unsigned short* Ksc = (const unsigned short*)(smem + cur * 8192);
        const unsigned short* Vsc = (const unsigned short*)(smem + 24576 + cur * 8192);

        // K A-frags (m = physical kcol row = kh*32 + l31, k = d):
        // logical d-chunk c = ks*2 + lh; physical chunk = c ^ (row&7), row&7 = lane&7.
        bf16x8 kA[4];
        #pragma unroll
        for (int ks = 0; ks < 4; ++ks)
            kA[ks] = *(const bf16x8*)&Ksc[(kh * 32 + l31) * 64 + (((ks * 2 + lh) ^ (lane & 7))) * 8];
        // V B-frags (k = kcol, n = d = dt*32 + l31): logical chunk =
        // kh*4 + kc*2 + lh; physical = ^ (d&7) = ^ (lane&7).
        bf16x8 bv[2][2];
        #pragma unroll
        for (int dt = 0; dt < 2; ++dt)
            #pragma unroll
            for (int kc = 0; kc < 2; ++kc)
                bv[dt][kc] = *(const bf16x8*)&Vsc[(dt * 32 + l31) * 64 +
                                                  (((kh * 4 + kc * 2 + lh) ^ (lane & 7))) * 8];

        bf16x8 ap[2][2];
        #pragma unroll
        for (int qt = 0; qt < 2; ++qt) {
            f32x16 sv;
            #pragma unroll
            for (int i = 0; i < 16; ++i) sv[i] = 0.f;
            #pragma unroll
            for (int ks = 0; ks < 4; ++ks)
                sv = MFMA32(kA[ks], aq[qt][ks], sv);
            float p[16];
            #pragma unroll
            for (int i = 0; i < 16; ++i) p[i] = __builtin_amdgcn_exp2f(sv[i]);
            union { unsigned int u[4]; bf16x8 v; } a0, a1;
            #pragma unroll
            for (int j = 0; j < 4; ++j) {
                a0.u[j] = pack_bf16_trunc(p[2 * j], p[2 * j + 1]);
                a1.u[j] = pack_bf16_trunc(p[8 + 2 * j], p[8 + 2 * j + 1]);
            }
            ap[qt][0] = a0.v;
            ap[qt][1] = a1.v;
            ol[qt] = MFMA32(ap[qt][0], ones8, ol[qt]);
            ol[qt] = MFMA32(ap[qt][1], ones8, ol[qt]);
        }
        #pragma unroll
        for (int qt = 0; qt < 2; ++qt)
            #pragma unroll
            for (int dt = 0; dt < 2; ++dt) {
                o[qt][dt] = MFMA32(ap[qt][0], bv[dt][0], o[qt][dt]);
                o[qt][dt] = MFMA32(ap[qt][1], bv[dt][1], o[qt][dt]);
            }
        cur = (cur == 2) ? 0 : cur + 1;
    }
#undef STAGE

    // ---- epilogue. Ored [4 w][32 q][64 d] f32 @0; Lred [4 w][2 qt][32 q] @32768.
    __syncthreads();   // all waves done with K/V buffers
    float* Ored = (float*)smem;
    float* Lred = (float*)(smem + 32768);
    if (l31 == 0) {    // lanes 0 and 32: ones-D cols all equal; rows = q
        #pragma unroll
        for (int qt = 0; qt < 2; ++qt)
            #pragma unroll
            for (int r = 0; r < 16; ++r)
                Lred[(wave * 2 + qt) * 32 + (r & 3) + 8 * (r >> 2) + 4 * lh] = ol[qt][r];
    }
    #pragma unroll
    for (int qt = 0; qt < 2; ++qt) {
        #pragma unroll
        for (int dt = 0; dt < 2; ++dt)
            #pragma unroll
            for (int r = 0; r < 16; ++r)
                Ored[wave * 2048 + ((r & 3) + 8 * (r >> 2) + 4 * lh) * 64 + dt * 32 + l31]
                    = o[qt][dt][r];
        __syncthreads();
        {
            int row6 = tid >> 2, dq = tid & 3;     // 64 out-rows x 4 d-quads
            int qh2 = row6 >> 5, qq = row6 & 31;
            const float* r0p = Ored + (qh2 * 2 + 0) * 2048 + qq * 64 + dq * 16;
            const float* r1p = Ored + (qh2 * 2 + 1) * 2048 + qq * 64 + dq * 16;
            float lt = Lred[((qh2 * 2 + 0) * 2 + qt) * 32 + qq] +
                       Lred[((qh2 * 2 + 1) * 2 + qt) * 32 + qq];
            float inv = 1.f / lt;
            size_t row = qrow0 + qh2 * 64 + qt * 32 + qq;
            unsigned short* dst = &Ab[row * EMB + h * 64 + dq * 16];
            #pragma unroll
            for (int i = 0; i < 4; ++i) {
                float4 a = *(const float4*)&r0p[i * 4];
                float4 c = *(const float4*)&r1p[i * 4];
                ushort4 pk = { f_to_bf16((a.x + c.x) * inv), f_to_bf16((a.y + c.y) * inv),
                               f_to_bf16((a.z + c.z) * inv), f_to_bf16((a.w + c.w) * inv) };
                *(ushort4*)&dst[i * 4] = pk;
            }
        }
        __syncthreads();
    }
}

// ---- Fused O-proj + residual + LayerNorm (R18, unchanged).
__global__ __launch_bounds__(256) void oproj_ln_kernel(
        const unsigned short* __restrict__ Ab, const unsigned short* __restrict__ Wo,
        const float* __restrict__ bias_all,
        const float* __restrict__ xf, const unsigned short* __restrict__ xraw,
        void* __restrict__ out) {
    __shared__ __align__(16) unsigned short Aslds[32 * 512];   // 32KB; later = P-tile
    int fp32 = detect_fp32(xraw);
    int tid = threadIdx.x;
    int wave = tid >> 6, lane = tid & 63;
    int l15 = lane & 15, quad = lane >> 4;
    int m0 = blockIdx.x * 32;

    {
        int c = lane;
        #pragma unroll
        for (int j = 0; j < 8; ++j) {
            int row = j * 4 + wave;
            int csrc = c ^ (row & 7);
            load_lds16(&Ab[(size_t)(m0 + row) * 512 + csrc * 8],
                       &Aslds[row * 512 + c * 8]);
        }
    }
    asm volatile("s_waitcnt vmcnt(0)" ::: "memory");
    __syncthreads();

    f32x4 acc[2][8];
    #pragma unroll
    for (int mf = 0; mf < 2; ++mf)
        #pragma unroll
        for (int nf = 0; nf < 8; ++nf) acc[mf][nf] = (f32x4){0.f, 0.f, 0.f, 0.f};

    const unsigned short* bgl = Wo + (size_t)(wave * 128 + l15) * 512 + quad * 8;

    #pragma unroll
    for (int s = 0; s < 8; ++s) {
        bf16x8 b[2][8];
        #pragma unroll
        for (int ks = 0; ks < 2; ++ks)
            #pragma unroll
            for (int nf = 0; nf < 8; ++nf)
                b[ks][nf] = *(const bf16x8*)&bgl[(size_t)nf * (16 * 512) + s * 64 + ks * 32];
        bf16x8 a[2][2];
        #pragma unroll
        for (int ks = 0; ks < 2; ++ks)
            #pragma unroll
            for (int mf = 0; mf < 2; ++mf) {
                int row = mf * 16 + l15;
                int clog = s * 8 + ks * 4 + quad;
                a[ks][mf] = *(const bf16x8*)&Aslds[row * 512 + (clog ^ (row & 7)) * 8];
            }
        #pragma unroll
        for (int ks = 0; ks < 2; ++ks)
            #pragma unroll
            for (int mf = 0; mf < 2; ++mf)
                #pragma unroll
                for (int nf = 0; nf < 8; ++nf)
                    acc[mf][nf] = __builtin_amdgcn_mfma_f32_16x16x32_bf16(a[ks][mf], b[ks][nf], acc[mf][nf], 0, 0, 0);
    }

    __syncthreads();   // everyone done reading A
    #pragma unroll
    for (int mf = 0; mf < 2; ++mf)
        #pragma unroll
        for (int nf = 0; nf < 8; ++nf) {
            int col = wave * 128 + nf * 16 + l15;
            float bo = bias_all[1536 + col];
            #pragma unroll
            for (int r = 0; r < 4; ++r) {
                int row = mf * 16 + quad * 4 + r;
                Aslds[row * 512 + col] = f_to_bf16(acc[mf][nf][r] + bo);
            }
        }
    __syncthreads();

    const float* gamma = bias_all + 4 * 512;
    const float* beta  = bias_all + 5 * 512;
    float g[8], bt[8];
    #pragma unroll
    for (int i = 0; i < 8; ++i) { g[i] = gamma[lane * 8 + i]; bt[i] = beta[lane * 8 + i]; }

    #pragma unroll
    for (int rr = 0; rr < 8; ++rr) {
        int row = wave * 8 + rr;
        size_t grow = (size_t)(m0 + row);
        const unsigned short* pp = &Aslds[row * 512 + lane * 8];
        ushort4 p0 = *(const ushort4*)&pp[0];
        ushort4 p1 = *(const ushort4*)&pp[4];
        float pv[8] = { bf16_to_f(p0.x), bf16_to_f(p0.y), bf16_to_f(p0.z), bf16_to_f(p0.w),
                        bf16_to_f(p1.x), bf16_to_f(p1.y), bf16_to_f(p1.z), bf16_to_f(p1.w) };
        float v[8];
        if (fp32) {
            const float* xp = &xf[grow * EMB + lane * 8];
            float4 x0 = *(const float4*)&xp[0];
            float4 x1 = *(const float4*)&xp[4];
            v[0] = x0.x + pv[0]; v[1] = x0.y + pv[1]; v[2] = x0.z + pv[2]; v[3] = x0.w + pv[3];
            v[4] = x1.x + pv[4]; v[5] = x1.y + pv[5]; v[6] = x1.z + pv[6]; v[7] = x1.w + pv[7];
        } else {
            const unsigned short* xp = &xraw[grow * EMB + lane * 8];
            ushort4 x0 = *(const ushort4*)&xp[0];
            ushort4 x1 = *(const ushort4*)&xp[4];
            v[0] = bf16_to_f(x0.x) + pv[0]; v[1] = bf16_to_f(x0.y) + pv[1];
            v[2] = bf16_to_f(x0.z) + pv[2]; v[3] = bf16_to_f(x0.w) + pv[3];
            v[4] = bf16_to_f(x1.x) + pv[4]; v[5] = bf16_to_f(x1.y) + pv[5];
            v[6] = bf16_to_f(x1.z) + pv[6]; v[7] = bf16_to_f(x1.w) + pv[7];
        }
        float s = 0.f, ss = 0.f;
        #pragma unroll
        for (int i = 0; i < 8; ++i) { s += v[i]; ss += v[i] * v[i]; }
        #pragma unroll
        for (int off = 32; off > 0; off >>= 1) {
            s  += __shfl_xor(s, off, 64);
            ss += __shfl_xor(ss, off, 64);
        }
        float mu = s * (1.f / 512.f);
        float var = ss * (1.f / 512.f) - mu * mu;
        float rs = rsqrtf(var + 1e-5f);
        if (fp32) {
            float* op = &((float*)out)[grow * EMB + lane * 8];
            float4 o0 = { (v[0] - mu) * rs * g[0] + bt[0], (v[1] - mu) * rs * g[1] + bt[1],
                          (v[2] - mu) * rs * g[2] + bt[2], (v[3] - mu) * rs * g[3] + bt[3] };
            float4 o1 = { (v[4] - mu) * rs * g[4] + bt[4], (v[5] - mu) * rs * g[5] + bt[5],
                          (v[6] - mu) * rs * g[6] + bt[6], (v[7] - mu) * rs * g[7] + bt[7] };
            *(float4*)&op[0] = o0;
            *(float4*)&op[4] = o1;
        } else {
            unsigned short* op = &((unsigned short*)out)[grow * EMB + lane * 8];
            ushort4 o0 = { f_to_bf16((v[0] - mu) * rs * g[0] + bt[0]),
                           f_to_bf16((v[1] - mu) * rs * g[1] + bt[1]),
                           f_to_bf16((v[2] - mu) * rs * g[2] + bt[2]),
                           f_to_bf16((v[3] - mu) * rs * g[3] + bt[3]) };
            ushort4 o1 = { f_to_bf16((v[4] - mu) * rs * g[4] + bt[4]),
                           f_to_bf16((v[5] - mu) * rs * g[5] + bt[5]),
                           f_to_bf16((v[6] - mu) * rs * g[6] + bt[6]),
                           f_to_bf16((v[7] - mu) * rs * g[7] + bt[7]) };
            *(ushort4*)&op[0] = o0;
            *(ushort4*)&op[4] = o1;
        }
    }
}

extern "C" void kernel_launch(void* const* d_in, const int* in_sizes, int n_in,
                              void* d_out, int out_size, void* d_ws, size_t ws_size,
                              hipStream_t stream) {
    char* ws = (char*)d_ws;
    char* p = ws + 256;
    float* bias_all = (float*)p;       p += 6 * 512 * 4;
    unsigned short* Wt   = (unsigned short*)p; p += (size_t)2048 * 512 * 2;  // 2MB
    unsigned short* QKVb = (unsigned short*)p; p += (size_t)ROWS * 1536 * 2; // 24MB
    unsigned short* Vt   = (unsigned short*)p; p += (size_t)16 * HD * SEQ * 2; // 8MB
    // shared region: xb (prep -> QKV gemm) then Ab (attn -> O-proj)
    unsigned short* xb = (unsigned short*)p;
    unsigned short* Ab = (unsigned short*)p;   p += (size_t)ROWS * EMB * 2;  // 8MB

    prep_kernel<<<4364, 256, 0, stream>>>(d_in[0], xb,
        d_in[1], d_in[3], d_in[5], d_in[7], Wt,
        d_in[2], d_in[4], d_in[6], d_in[8], d_in[9], d_in[10], bias_all);

    // fused QKV: N=1536; Q cols pre-scaled by QSCALE; V cols written transposed to Vt
    gemm_mfma_kernel<unsigned short><<<dim3(12, 64), 256, 0, stream>>>(
        xb, (const unsigned short*)d_in[0], Wt, bias_all, QKVb, 1536, 512, Vt);

    attn_kernel<<<dim3(512), 256, 0, stream>>>(QKVb, Vt, Ab);

    // fused O-proj + residual + LayerNorm
    oproj_ln_kernel<<<ROWS / 32, 256, 0, stream>>>(
        Ab, Wt + (size_t)1536 * 512, bias_all,
        (const float*)d_in[0], (const unsigned short*)d_in[0], d_out);
}